// Round 1
// baseline (132.213 us; speedup 1.0000x reference)
//
#include <hip/hip_runtime.h>
#include <stdint.h>

// Problem constants (fixed by setup_inputs).
#define N_LIDAR   8192
#define M_QUERIES 32768   // 1024 rays * 32 samples
#define D_FEAT    128
#define SEG_LEN   512
#define N_SEG     (N_LIDAR / SEG_LEN)      // 16
#define Q_PER_THREAD 4
#define BLOCK     256
#define Q_PER_BLOCK (BLOCK * Q_PER_THREAD) // 1024

// Workspace layout:
//   [0, N_LIDAR*16)                          : packed float4 (lx,ly,lz,ksq)
//   [N_LIDAR*16, N_LIDAR*16 + M_QUERIES*8)   : u64 argmin keys
#define WS_KEYS_OFF (N_LIDAR * 16)

// Kernel A: pack lidar points with precomputed ||k||^2, init keys.
__global__ __launch_bounds__(BLOCK)
void prep_kernel(const float* __restrict__ lidar,
                 float4* __restrict__ packed,
                 unsigned long long* __restrict__ keys) {
    #pragma clang fp contract(off)
    int i = blockIdx.x * blockDim.x + threadIdx.x;
    if (i < N_LIDAR) {
        float lx = lidar[3 * i + 0];
        float ly = lidar[3 * i + 1];
        float lz = lidar[3 * i + 2];
        // Match np.sum(k*k, -1) rounding: (lx^2 + ly^2) + lz^2, no FMA.
        float ks = (lx * lx + ly * ly) + lz * lz;
        packed[i] = make_float4(lx, ly, lz, ks);
    }
    if (i < M_QUERIES) keys[i] = 0xFFFFFFFFFFFFFFFFull;
}

// Kernel B: brute-force argmin over one lidar segment for 1024 queries/block.
// d2 = (qs - 2*cross) + ks, computed with the reference's f32 rounding order.
__global__ __launch_bounds__(BLOCK)
void argmin_kernel(const float* __restrict__ pts,
                   const float4* __restrict__ packed,
                   unsigned long long* __restrict__ keys) {
    #pragma clang fp contract(off)
    __shared__ float4 lds[SEG_LEN];
    const int tid   = threadIdx.x;
    const int qtile = blockIdx.x;
    const int seg   = blockIdx.y;

    // Stage this segment's 512 packed candidates into LDS (coalesced 16B/lane).
    for (int k = tid; k < SEG_LEN; k += BLOCK)
        lds[k] = packed[seg * SEG_LEN + k];

    float qx[Q_PER_THREAD], qy[Q_PER_THREAD], qz[Q_PER_THREAD], qs[Q_PER_THREAD];
    float bd[Q_PER_THREAD];
    int   bi[Q_PER_THREAD];
    #pragma unroll
    for (int qq = 0; qq < Q_PER_THREAD; ++qq) {
        int m = qtile * Q_PER_BLOCK + qq * BLOCK + tid;
        float x = pts[3 * m + 0];
        float y = pts[3 * m + 1];
        float z = pts[3 * m + 2];
        qx[qq] = x; qy[qq] = y; qz[qq] = z;
        // Match np.sum(q*q, -1) rounding: (x^2 + y^2) + z^2, no FMA.
        qs[qq] = (x * x + y * y) + z * z;
        bd[qq] = __builtin_inff();
        bi[qq] = 0;
    }
    __syncthreads();

    // Inner scan: broadcast LDS read (all lanes same address -> conflict-free),
    // amortized over Q_PER_THREAD queries. Strict < keeps FIRST min (np.argmin).
    for (int j = 0; j < SEG_LEN; ++j) {
        float4 p = lds[j];
        #pragma unroll
        for (int qq = 0; qq < Q_PER_THREAD; ++qq) {
            float m0 = qx[qq] * p.x;
            float m1 = qy[qq] * p.y;
            float m2 = qz[qq] * p.z;
            float c  = (m0 + m1) + m2;        // einsum order, no FMA
            float t  = qs[qq] - 2.0f * c;     // 2*c exact; single rounding
            float d2 = t + p.w;
            bool lt = d2 < bd[qq];
            bd[qq] = lt ? d2 : bd[qq];
            bi[qq] = lt ? j  : bi[qq];
        }
    }

    // Combine across segments via monotone u64 key: smaller d2 wins, ties ->
    // smaller global index (matches np.argmin first-occurrence semantics).
    #pragma unroll
    for (int qq = 0; qq < Q_PER_THREAD; ++qq) {
        int m = qtile * Q_PER_BLOCK + qq * BLOCK + tid;
        unsigned int u = __float_as_uint(bd[qq]);
        u ^= (u >> 31) ? 0xFFFFFFFFu : 0x80000000u;  // order-preserving (handles d2<0 from cancellation)
        unsigned long long key =
            ((unsigned long long)u << 13) |
            (unsigned long long)(seg * SEG_LEN + bi[qq]);
        atomicMin(&keys[m], key);
    }
}

// Kernel C: gather 128 f32 features per query (32 lanes * float4 per query).
__global__ __launch_bounds__(BLOCK)
void gather_kernel(const unsigned long long* __restrict__ keys,
                   const float4* __restrict__ feat,
                   float4* __restrict__ out) {
    int t    = blockIdx.x * blockDim.x + threadIdx.x;
    int q    = t >> 5;         // 32 lanes per query
    int lane = t & 31;
    unsigned long long key = keys[q];
    int idx = (int)(key & (unsigned long long)(N_LIDAR - 1));
    out[q * (D_FEAT / 4) + lane] = feat[idx * (D_FEAT / 4) + lane];
}

extern "C" void kernel_launch(void* const* d_in, const int* in_sizes, int n_in,
                              void* d_out, int out_size, void* d_ws, size_t ws_size,
                              hipStream_t stream) {
    const float* pts      = (const float*)d_in[0];   // (1,1024,32,3)
    const float* lidar    = (const float*)d_in[1];   // (1,8192,3)
    const float* features = (const float*)d_in[2];   // (1,8192,128)
    float* out = (float*)d_out;                      // (1,1024,32,128)

    float4* packed = (float4*)d_ws;
    unsigned long long* keys = (unsigned long long*)((char*)d_ws + WS_KEYS_OFF);

    prep_kernel<<<M_QUERIES / BLOCK, BLOCK, 0, stream>>>(lidar, packed, keys);
    argmin_kernel<<<dim3(M_QUERIES / Q_PER_BLOCK, N_SEG), BLOCK, 0, stream>>>(
        pts, packed, keys);
    gather_kernel<<<(M_QUERIES * 32) / BLOCK, BLOCK, 0, stream>>>(
        keys, (const float4*)features, (float4*)out);
}